// Round 2
// baseline (2306.498 us; speedup 1.0000x reference)
//
#include <hip/hip_runtime.h>

#define NN 50000
#define NE 800000
#define HD 128
#define DEPTH 5
#define NG 64
#define LNEPS 1e-5f

typedef __attribute__((ext_vector_type(8))) short bf8;   // 8 x bf16
typedef __attribute__((ext_vector_type(4))) float f4;

static __device__ __forceinline__ unsigned short f2bf(float x) {
    unsigned int u = __float_as_uint(x);
    unsigned int r = (u + 0x7fffu + ((u >> 16) & 1u)) >> 16;   // RNE
    return (unsigned short)r;
}

// ---------------------------------------------------------------------------
// Pack weight matrices (K x 128 f32, row-major) into bf16 MFMA B-fragment
// layout: packed[s*4096 + f*512 + lane*8 + e] = W[s*32 + (lane>>4)*8 + e][f*16 + (lane&15)]
// ---------------------------------------------------------------------------
__global__ void pack_weights(const float* __restrict__ msg_w1, const float* __restrict__ msg_w2,
                             const float* __restrict__ upd_w1, const float* __restrict__ upd_w2,
                             unsigned short* __restrict__ packed) {
    const int which = blockIdx.y & 3, layer = blockIdx.y >> 2;
    const int t = blockIdx.x * 256 + threadIdx.x;
    const float* src; int K; unsigned short* dst;
    unsigned short* lbase = packed + layer * 98304;
    if (which == 0)      { src = msg_w1 + layer*257*HD; K = 256; dst = lbase; }
    else if (which == 1) { src = msg_w2 + layer*HD*HD;  K = 128; dst = lbase + 32768; }
    else if (which == 2) { src = upd_w1 + layer*256*HD; K = 256; dst = lbase + 49152; }
    else                 { src = upd_w2 + layer*HD*HD;  K = 128; dst = lbase + 81920; }
    if (t >= K * HD) return;
    const int e = t & 7, l = (t >> 3) & 63, f = (t >> 9) & 7, s = t >> 12;
    const int k = s*32 + ((l >> 4) << 3) + e;
    const int n = f*16 + (l & 15);
    dst[t] = f2bf(src[k*HD + n]);
}

__global__ void embed_kernel(const float* __restrict__ x, const float* __restrict__ emb_w,
                             const float* __restrict__ emb_b,
                             float* __restrict__ h, unsigned short* __restrict__ hb) {
    const int i = blockIdx.x * 256 + threadIdx.x;      // N*H exact
    const int n = i >> 7, j = i & 127;
    const float v = x[n] * emb_w[j] + emb_b[j];
    h[i] = v; hb[i] = f2bf(v);
}

// --------------------- counting sort of edges by dst -----------------------
__global__ void hist_kernel(const int* __restrict__ ei, int* __restrict__ cnt) {
    const int e = blockIdx.x * 256 + threadIdx.x;      // NE exact
    atomicAdd(&cnt[ei[NE + e]], 1);
}

// single block, 1024 threads: exclusive scan of cnt[NN] -> cur[NN]
__global__ __launch_bounds__(1024) void scan_kernel(const int* __restrict__ cnt,
                                                    int* __restrict__ cur) {
    __shared__ int part[1024];
    const int t = threadIdx.x;
    const int per = 49;                                 // 1024*49 >= NN
    const int base = t * per;
    int s = 0;
    for (int i = 0; i < per; ++i) { const int idx = base + i; if (idx < NN) s += cnt[idx]; }
    part[t] = s; __syncthreads();
    for (int st = 1; st < 1024; st <<= 1) {
        const int v = (t >= st) ? part[t - st] : 0;
        __syncthreads();
        part[t] += v;
        __syncthreads();
    }
    int run = (t == 0) ? 0 : part[t - 1];
    for (int i = 0; i < per; ++i) {
        const int idx = base + i;
        if (idx < NN) { cur[idx] = run; run += cnt[idx]; }
    }
}

__global__ void scatter_kernel(const int* __restrict__ ei, int* __restrict__ cur,
                               int* __restrict__ sidx, int* __restrict__ ssrc,
                               int* __restrict__ sdst) {
    const int e = blockIdx.x * 256 + threadIdx.x;      // NE exact
    const int d = ei[NE + e];
    const int p = atomicAdd(&cur[d], 1);
    sidx[p] = e; ssrc[p] = ei[e]; sdst[p] = d;
}

// dist in SORTED edge order
__global__ void dist_kernel(const float* __restrict__ pos, const int* __restrict__ sidx,
                            const int* __restrict__ ssrc, const int* __restrict__ sdst,
                            const float* __restrict__ cell, const float* __restrict__ U,
                            float* __restrict__ dist) {
    const int p = blockIdx.x * 256 + threadIdx.x;      // NE exact
    const int e = sidx[p];
    const int s = ssrc[p], d = sdst[p];
    const float c0 = cell[e*3], c1 = cell[e*3+1], c2 = cell[e*3+2];
    const float ox = c0*U[0] + c1*U[3] + c2*U[6];
    const float oy = c0*U[1] + c1*U[4] + c2*U[7];
    const float oz = c0*U[2] + c1*U[5] + c2*U[8];
    const float dx = pos[d*3]   - ox - pos[s*3];
    const float dy = pos[d*3+1] - oy - pos[s*3+1];
    const float dz = pos[d*3+2] - oz - pos[s*3+2];
    dist[p] = sqrtf(dx*dx + dy*dy + dz*dz);
}

// ---------------------------------------------------------------------------
// Edge MLP over dst-sorted edges, 64/block. GEMM1(K=256)->LN->relu->bf16 LDS
// ->GEMM2(K=128)->LN->relu-> f32 msg into LDS -> block segmented reduce ->
// few coalesced atomics per distinct dst.
// ---------------------------------------------------------------------------
__global__ __launch_bounds__(256) void edge_kernel(
    const unsigned short* __restrict__ hb, const float* __restrict__ dist,
    const int* __restrict__ ssrc, const int* __restrict__ sdst,
    const unsigned short* __restrict__ pw,
    const float* __restrict__ w1last, const float* __restrict__ b1,
    const float* __restrict__ g1, const float* __restrict__ be1,
    const float* __restrict__ b2, const float* __restrict__ g2,
    const float* __restrict__ be2, float* __restrict__ aggr)
{
    __shared__ unsigned short lds[64 * 256];           // 64 rows x 512B (A-tile, then f32 msg)
    __shared__ int dstl[64];
    char* ldsb = (char*)lds;
    float* ldsf = (float*)lds;
    const int tid = threadIdx.x, blk = blockIdx.x;

    if (tid < 64) dstl[tid] = sdst[blk*64 + tid];
    {   // stage: thread t -> row t>>2, 128B quarter (part)
        const int row = tid >> 2, part = tid & 3;
        const int edge = blk*64 + row;
        const int node = (part < 2) ? sdst[edge] : ssrc[edge];   // dst | src
        const unsigned short* sp = hb + node*HD + (part & 1)*64;
        const int base = row*512 + part*128;
        #pragma unroll
        for (int c = 0; c < 8; ++c) {
            uint4 v = *(const uint4*)(sp + c*8);
            *(uint4*)(ldsb + ((base + c*16) ^ ((row & 7) << 4))) = v;
        }
    }
    __syncthreads();

    const int l = tid & 63, wv = tid >> 6;
    const int mbase = wv * 16;
    const int li = l & 15, gq = l >> 4;
    const int arow = mbase + li;
    const int asw = (arow & 7) << 4;

    f4 acc[8];
    #pragma unroll
    for (int f = 0; f < 8; ++f) { f4 z = {0.f,0.f,0.f,0.f}; acc[f] = z; }
    #pragma unroll
    for (int s = 0; s < 8; ++s) {
        bf8 a = *(const bf8*)(ldsb + ((arow*512 + s*64 + gq*16) ^ asw));
        #pragma unroll
        for (int f = 0; f < 8; ++f) {
            bf8 b = *(const bf8*)(pw + s*4096 + f*512 + l*8);
            acc[f] = __builtin_amdgcn_mfma_f32_16x16x32_bf16(a, b, acc[f], 0, 0, 0);
        }
    }

    // epilogue 1: +b1 +dist*w1last -> LN -> relu -> bf16 back to LDS row head
    float dsv[4];
    #pragma unroll
    for (int r = 0; r < 4; ++r) dsv[r] = dist[blk*64 + mbase + gq*4 + r];
    float bb[8], wl[8];
    float ps[4] = {0,0,0,0}, pq[4] = {0,0,0,0};
    #pragma unroll
    for (int f = 0; f < 8; ++f) {
        const int n = f*16 + li;
        bb[f] = b1[n]; wl[f] = w1last[n];
        #pragma unroll
        for (int r = 0; r < 4; ++r) {
            const float v = acc[f][r] + bb[f] + dsv[r]*wl[f];
            ps[r] += v; pq[r] += v*v;
        }
    }
    #pragma unroll
    for (int m = 1; m < 16; m <<= 1) {
        #pragma unroll
        for (int r = 0; r < 4; ++r) {
            ps[r] += __shfl_xor(ps[r], m);
            pq[r] += __shfl_xor(pq[r], m);
        }
    }
    #pragma unroll
    for (int r = 0; r < 4; ++r) {
        const float mean = ps[r] * (1.f/HD);
        const float rstd = rsqrtf(pq[r]*(1.f/HD) - mean*mean + LNEPS);
        const int row = mbase + gq*4 + r;
        const int rsw = (row & 7) << 4;
        #pragma unroll
        for (int f = 0; f < 8; ++f) {
            const int n = f*16 + li;
            float v = (acc[f][r] + bb[f] + dsv[r]*wl[f] - mean)*rstd*g1[n] + be1[n];
            v = fmaxf(v, 0.f);
            *(unsigned short*)(ldsb + ((row*512 + n*2) ^ rsw)) = f2bf(v);
        }
    }
    // rows are wave-private: no barrier before GEMM2

    const unsigned short* pw2 = pw + 32768;
    f4 acc2[8];
    #pragma unroll
    for (int f = 0; f < 8; ++f) { f4 z = {0.f,0.f,0.f,0.f}; acc2[f] = z; }
    #pragma unroll
    for (int s = 0; s < 4; ++s) {
        bf8 a = *(const bf8*)(ldsb + ((arow*512 + s*64 + gq*16) ^ asw));
        #pragma unroll
        for (int f = 0; f < 8; ++f) {
            bf8 b = *(const bf8*)(pw2 + s*4096 + f*512 + l*8);
            acc2[f] = __builtin_amdgcn_mfma_f32_16x16x32_bf16(a, b, acc2[f], 0, 0, 0);
        }
    }

    // epilogue 2: +b2 -> LN -> relu -> f32 msg into LDS (bank-rotated)
    float bb2[8];
    float ps2[4] = {0,0,0,0}, pq2[4] = {0,0,0,0};
    #pragma unroll
    for (int f = 0; f < 8; ++f) {
        bb2[f] = b2[f*16 + li];
        #pragma unroll
        for (int r = 0; r < 4; ++r) {
            const float v = acc2[f][r] + bb2[f];
            ps2[r] += v; pq2[r] += v*v;
        }
    }
    #pragma unroll
    for (int m = 1; m < 16; m <<= 1) {
        #pragma unroll
        for (int r = 0; r < 4; ++r) {
            ps2[r] += __shfl_xor(ps2[r], m);
            pq2[r] += __shfl_xor(pq2[r], m);
        }
    }
    #pragma unroll
    for (int r = 0; r < 4; ++r) {
        const float mean = ps2[r] * (1.f/HD);
        const float rstd = rsqrtf(pq2[r]*(1.f/HD) - mean*mean + LNEPS);
        const int row = mbase + gq*4 + r;
        #pragma unroll
        for (int f = 0; f < 8; ++f) {
            const int n = f*16 + li;
            float v = (acc2[f][r] + bb2[f] - mean)*rstd*g2[n] + be2[n];
            ldsf[row*128 + ((n + 4*row) & 127)] = fmaxf(v, 0.f);
        }
    }
    __syncthreads();

    // segmented reduction over 64 sorted rows: thread = (col j, half hh)
    {
        const int j = tid & 127, hh = tid >> 7;
        const int r0 = hh * 32;
        int curd = dstl[r0];
        float acc3 = 0.f;
        #pragma unroll 4
        for (int i = 0; i < 32; ++i) {
            const int row = r0 + i;
            const int d = dstl[row];
            const float v = ldsf[row*128 + ((j + 4*row) & 127)];
            if (d != curd) { unsafeAtomicAdd(&aggr[curd*HD + j], acc3); acc3 = 0.f; curd = d; }
            acc3 += v;
        }
        unsafeAtomicAdd(&aggr[curd*HD + j], acc3);
    }
}

// ---------------------------------------------------------------------------
// Node update: A = [h | aggr] (K=256). Residual h += u, refresh hb,
// zero aggr in-place for the next layer.
// ---------------------------------------------------------------------------
__global__ __launch_bounds__(256) void node_kernel(
    unsigned short* __restrict__ hb, float* __restrict__ aggr,
    const unsigned short* __restrict__ pw,
    const float* __restrict__ b1, const float* __restrict__ g1, const float* __restrict__ be1,
    const float* __restrict__ b2, const float* __restrict__ g2, const float* __restrict__ be2,
    float* __restrict__ h)
{
    __shared__ unsigned short lds[64 * 256];
    char* ldsb = (char*)lds;
    const int tid = threadIdx.x, blk = blockIdx.x;

    {
        const int row = tid >> 2, part = tid & 3;
        const int node = blk*64 + row;
        const int base = row*512 + part*128;
        if (node < NN) {
            if (part < 2) {
                const unsigned short* sp = hb + node*HD + part*64;
                #pragma unroll
                for (int c = 0; c < 8; ++c) {
                    uint4 v = *(const uint4*)(sp + c*8);
                    *(uint4*)(ldsb + ((base + c*16) ^ ((row & 7) << 4))) = v;
                }
            } else {
                float* ap = aggr + node*HD + (part - 2)*64;
                #pragma unroll
                for (int c = 0; c < 8; ++c) {
                    float4 v0 = *(const float4*)(ap + c*8);
                    float4 v1 = *(const float4*)(ap + c*8 + 4);
                    union { unsigned short u[8]; uint4 v; } pk;
                    pk.u[0]=f2bf(v0.x); pk.u[1]=f2bf(v0.y); pk.u[2]=f2bf(v0.z); pk.u[3]=f2bf(v0.w);
                    pk.u[4]=f2bf(v1.x); pk.u[5]=f2bf(v1.y); pk.u[6]=f2bf(v1.z); pk.u[7]=f2bf(v1.w);
                    *(uint4*)(ldsb + ((base + c*16) ^ ((row & 7) << 4))) = pk.v;
                }
                const float4 z = {0.f,0.f,0.f,0.f};
                #pragma unroll
                for (int c = 0; c < 16; ++c) *(float4*)(ap + c*4) = z;  // ready for next layer
            }
        } else {
            const uint4 z = {0,0,0,0};
            #pragma unroll
            for (int c = 0; c < 8; ++c)
                *(uint4*)(ldsb + ((base + c*16) ^ ((row & 7) << 4))) = z;
        }
    }
    __syncthreads();

    const int l = tid & 63, wv = tid >> 6;
    const int mbase = wv * 16;
    const int li = l & 15, gq = l >> 4;
    const int arow = mbase + li;
    const int asw = (arow & 7) << 4;

    f4 acc[8];
    #pragma unroll
    for (int f = 0; f < 8; ++f) { f4 z = {0.f,0.f,0.f,0.f}; acc[f] = z; }
    #pragma unroll
    for (int s = 0; s < 8; ++s) {
        bf8 a = *(const bf8*)(ldsb + ((arow*512 + s*64 + gq*16) ^ asw));
        #pragma unroll
        for (int f = 0; f < 8; ++f) {
            bf8 b = *(const bf8*)(pw + s*4096 + f*512 + l*8);
            acc[f] = __builtin_amdgcn_mfma_f32_16x16x32_bf16(a, b, acc[f], 0, 0, 0);
        }
    }

    float bb[8];
    float ps[4] = {0,0,0,0}, pq[4] = {0,0,0,0};
    #pragma unroll
    for (int f = 0; f < 8; ++f) {
        bb[f] = b1[f*16 + li];
        #pragma unroll
        for (int r = 0; r < 4; ++r) {
            const float v = acc[f][r] + bb[f];
            ps[r] += v; pq[r] += v*v;
        }
    }
    #pragma unroll
    for (int m = 1; m < 16; m <<= 1) {
        #pragma unroll
        for (int r = 0; r < 4; ++r) {
            ps[r] += __shfl_xor(ps[r], m);
            pq[r] += __shfl_xor(pq[r], m);
        }
    }
    #pragma unroll
    for (int r = 0; r < 4; ++r) {
        const float mean = ps[r] * (1.f/HD);
        const float rstd = rsqrtf(pq[r]*(1.f/HD) - mean*mean + LNEPS);
        const int row = mbase + gq*4 + r;
        const int rsw = (row & 7) << 4;
        #pragma unroll
        for (int f = 0; f < 8; ++f) {
            const int n = f*16 + li;
            float v = (acc[f][r] + bb[f] - mean)*rstd*g1[n] + be1[n];
            v = fmaxf(v, 0.f);
            *(unsigned short*)(ldsb + ((row*512 + n*2) ^ rsw)) = f2bf(v);
        }
    }

    const unsigned short* pw2 = pw + 32768;
    f4 acc2[8];
    #pragma unroll
    for (int f = 0; f < 8; ++f) { f4 z = {0.f,0.f,0.f,0.f}; acc2[f] = z; }
    #pragma unroll
    for (int s = 0; s < 4; ++s) {
        bf8 a = *(const bf8*)(ldsb + ((arow*512 + s*64 + gq*16) ^ asw));
        #pragma unroll
        for (int f = 0; f < 8; ++f) {
            bf8 b = *(const bf8*)(pw2 + s*4096 + f*512 + l*8);
            acc2[f] = __builtin_amdgcn_mfma_f32_16x16x32_bf16(a, b, acc2[f], 0, 0, 0);
        }
    }

    float bb2[8];
    float ps2[4] = {0,0,0,0}, pq2[4] = {0,0,0,0};
    #pragma unroll
    for (int f = 0; f < 8; ++f) {
        bb2[f] = b2[f*16 + li];
        #pragma unroll
        for (int r = 0; r < 4; ++r) {
            const float v = acc2[f][r] + bb2[f];
            ps2[r] += v; pq2[r] += v*v;
        }
    }
    #pragma unroll
    for (int m = 1; m < 16; m <<= 1) {
        #pragma unroll
        for (int r = 0; r < 4; ++r) {
            ps2[r] += __shfl_xor(ps2[r], m);
            pq2[r] += __shfl_xor(pq2[r], m);
        }
    }
    #pragma unroll
    for (int r = 0; r < 4; ++r) {
        const int node = blk*64 + mbase + gq*4 + r;
        if (node < NN) {
            const float mean = ps2[r] * (1.f/HD);
            const float rstd = rsqrtf(pq2[r]*(1.f/HD) - mean*mean + LNEPS);
            #pragma unroll
            for (int f = 0; f < 8; ++f) {
                const int n = f*16 + li;
                float v = (acc2[f][r] + bb2[f] - mean)*rstd*g2[n] + be2[n];
                v = fmaxf(v, 0.f);
                const int idx = node*HD + n;
                const float nh = h[idx] + v;
                h[idx] = nh;
                hb[idx] = f2bf(nh);
            }
        }
    }
}

// global_add_pool over sorted batch_ids
__global__ void pool_kernel(const float* __restrict__ h, const int* __restrict__ bids,
                            float* __restrict__ pooled) {
    const int j = threadIdx.x;                  // 128 features
    const int n0 = blockIdx.x * 256;
    if (n0 >= NN) return;
    int cur = bids[n0];
    float acc = 0.f;
    for (int i = 0; i < 256; ++i) {
        const int n = n0 + i;
        if (n >= NN) break;
        const int b = bids[n];
        if (b != cur) { unsafeAtomicAdd(&pooled[cur*HD + j], acc); acc = 0.f; cur = b; }
        acc += h[n*HD + j];
    }
    unsafeAtomicAdd(&pooled[cur*HD + j], acc);
}

__global__ void pred_kernel(const float* __restrict__ pooled, const float* __restrict__ w1,
                            const float* __restrict__ pb1, const float* __restrict__ w2,
                            const float* __restrict__ pb2, float* __restrict__ out) {
    const int g = blockIdx.x, j = threadIdx.x;  // 128 threads
    __shared__ float pg[128];
    __shared__ float red[128];
    pg[j] = pooled[g*HD + j];
    __syncthreads();
    float z = pb1[j];
    for (int k = 0; k < 128; ++k) z += pg[k] * w1[k*HD + j];
    red[j] = fmaxf(z, 0.f) * w2[j];
    __syncthreads();
    for (int st = 64; st > 0; st >>= 1) {
        if (j < st) red[j] += red[j + st];
        __syncthreads();
    }
    if (j == 0) out[g] = red[0] + pb2[0];
}

extern "C" void kernel_launch(void* const* d_in, const int* in_sizes, int n_in,
                              void* d_out, int out_size, void* d_ws, size_t ws_size,
                              hipStream_t stream) {
    const float* x       = (const float*)d_in[0];
    const float* pos     = (const float*)d_in[1];
    const int*   ei      = (const int*)  d_in[2];
    const float* cell    = (const float*)d_in[3];
    const float* U       = (const float*)d_in[4];
    const int*   bids    = (const int*)  d_in[5];
    const float* emb_w   = (const float*)d_in[6];
    const float* emb_b   = (const float*)d_in[7];
    const float* msg_w1  = (const float*)d_in[8];
    const float* msg_b1  = (const float*)d_in[9];
    const float* msg_g1  = (const float*)d_in[10];
    const float* msg_be1 = (const float*)d_in[11];
    const float* msg_w2  = (const float*)d_in[12];
    const float* msg_b2  = (const float*)d_in[13];
    const float* msg_g2  = (const float*)d_in[14];
    const float* msg_be2 = (const float*)d_in[15];
    const float* upd_w1  = (const float*)d_in[16];
    const float* upd_b1  = (const float*)d_in[17];
    const float* upd_g1  = (const float*)d_in[18];
    const float* upd_be1 = (const float*)d_in[19];
    const float* upd_w2  = (const float*)d_in[20];
    const float* upd_b2  = (const float*)d_in[21];
    const float* upd_g2  = (const float*)d_in[22];
    const float* upd_be2 = (const float*)d_in[23];
    const float* pred_w1 = (const float*)d_in[24];
    const float* pred_b1 = (const float*)d_in[25];
    const float* pred_w2 = (const float*)d_in[26];
    const float* pred_b2 = (const float*)d_in[27];

    char* ws = (char*)d_ws;
    float*          h      = (float*)          ws;                 // 25,600,000
    unsigned short* hb     = (unsigned short*)(ws + 25600000);     // 12,800,000
    float*          aggr   = (float*)         (ws + 38400000);     // 25,600,000
    float*          dist   = (float*)         (ws + 64000000);     //  3,200,000
    float*          pooled = (float*)         (ws + 67200000);     //     32,768
    unsigned short* packed = (unsigned short*)(ws + 67232768);     //    983,040
    int*            cnt    = (int*)           (ws + 68215808);     //    200,704
    int*            cur    = (int*)           (ws + 68416512);     //    200,704
    int*            sidx   = (int*)           (ws + 68617216);     //  3,200,000
    int*            ssrc   = (int*)           (ws + 71817216);     //  3,200,000
    int*            sdst   = (int*)           (ws + 75017216);     //  3,200,000

    hipMemsetAsync(aggr, 0, (size_t)NN * HD * sizeof(float), stream);
    hipMemsetAsync(pooled, 0, (size_t)NG * HD * sizeof(float), stream);
    hipMemsetAsync(cnt, 0, (size_t)NN * sizeof(int), stream);

    dim3 pgrid(128, DEPTH * 4);
    pack_weights<<<pgrid, 256, 0, stream>>>(msg_w1, msg_w2, upd_w1, upd_w2, packed);
    embed_kernel<<<(NN * HD) / 256, 256, 0, stream>>>(x, emb_w, emb_b, h, hb);

    hist_kernel<<<NE / 256, 256, 0, stream>>>(ei, cnt);
    scan_kernel<<<1, 1024, 0, stream>>>(cnt, cur);
    scatter_kernel<<<NE / 256, 256, 0, stream>>>(ei, cur, sidx, ssrc, sdst);
    dist_kernel<<<NE / 256, 256, 0, stream>>>(pos, sidx, ssrc, sdst, cell, U, dist);

    for (int layer = 0; layer < DEPTH; ++layer) {
        const unsigned short* pl = packed + layer * 98304;
        edge_kernel<<<NE / 64, 256, 0, stream>>>(
            hb, dist, ssrc, sdst, pl,
            msg_w1 + layer*257*HD + 256*HD,
            msg_b1 + layer*HD, msg_g1 + layer*HD, msg_be1 + layer*HD,
            msg_b2 + layer*HD, msg_g2 + layer*HD, msg_be2 + layer*HD,
            aggr);
        node_kernel<<<(NN + 63) / 64, 256, 0, stream>>>(
            hb, aggr, pl + 49152,
            upd_b1 + layer*HD, upd_g1 + layer*HD, upd_be1 + layer*HD,
            upd_b2 + layer*HD, upd_g2 + layer*HD, upd_be2 + layer*HD,
            h);
    }

    pool_kernel<<<(NN + 255) / 256, 128, 0, stream>>>(h, bids, pooled);
    pred_kernel<<<NG, 128, 0, stream>>>(pooled, pred_w1, pred_b1, pred_w2, pred_b2, (float*)d_out);
}

// Round 3
// 2089.482 us; speedup vs baseline: 1.1039x; 1.1039x over previous
//
#include <hip/hip_runtime.h>

#define NN 50000
#define NE 800000
#define HD 128
#define DEPTH 5
#define NG 64
#define LNEPS 1e-5f

typedef __attribute__((ext_vector_type(8))) short bf8;   // 8 x bf16
typedef __attribute__((ext_vector_type(4))) float f4;

static __device__ __forceinline__ unsigned short f2bf(float x) {
    unsigned int u = __float_as_uint(x);
    unsigned int r = (u + 0x7fffu + ((u >> 16) & 1u)) >> 16;   // RNE
    return (unsigned short)r;
}

// ---------------------------------------------------------------------------
// Pack weight matrices (K x 128 f32, row-major) into bf16 MFMA B-fragment
// layout: packed[s*4096 + f*512 + lane*8 + e] = W[s*32 + (lane>>4)*8 + e][f*16 + (lane&15)]
// ---------------------------------------------------------------------------
__global__ void pack_weights(const float* __restrict__ msg_w1, const float* __restrict__ msg_w2,
                             const float* __restrict__ upd_w1, const float* __restrict__ upd_w2,
                             unsigned short* __restrict__ packed) {
    const int which = blockIdx.y & 3, layer = blockIdx.y >> 2;
    const int t = blockIdx.x * 256 + threadIdx.x;
    const float* src; int K; unsigned short* dst;
    unsigned short* lbase = packed + layer * 98304;
    if (which == 0)      { src = msg_w1 + layer*257*HD; K = 256; dst = lbase; }
    else if (which == 1) { src = msg_w2 + layer*HD*HD;  K = 128; dst = lbase + 32768; }
    else if (which == 2) { src = upd_w1 + layer*256*HD; K = 256; dst = lbase + 49152; }
    else                 { src = upd_w2 + layer*HD*HD;  K = 128; dst = lbase + 81920; }
    if (t >= K * HD) return;
    const int e = t & 7, l = (t >> 3) & 63, f = (t >> 9) & 7, s = t >> 12;
    const int k = s*32 + ((l >> 4) << 3) + e;
    const int n = f*16 + (l & 15);
    dst[t] = f2bf(src[k*HD + n]);
}

__global__ void embed_kernel(const float* __restrict__ x, const float* __restrict__ emb_w,
                             const float* __restrict__ emb_b,
                             float* __restrict__ h, unsigned short* __restrict__ hb) {
    const int i = blockIdx.x * 256 + threadIdx.x;      // N*H exact
    const int n = i >> 7, j = i & 127;
    const float v = x[n] * emb_w[j] + emb_b[j];
    h[i] = v; hb[i] = f2bf(v);
}

// --------------------- counting sort of edges by dst -----------------------
__global__ void hist_kernel(const int* __restrict__ ei, int* __restrict__ cnt) {
    const int e = blockIdx.x * 256 + threadIdx.x;      // NE exact
    atomicAdd(&cnt[ei[NE + e]], 1);
}

__global__ __launch_bounds__(1024) void scan_kernel(const int* __restrict__ cnt,
                                                    int* __restrict__ cur) {
    __shared__ int part[1024];
    const int t = threadIdx.x;
    const int per = 49;                                 // 1024*49 >= NN
    const int base = t * per;
    int s = 0;
    for (int i = 0; i < per; ++i) { const int idx = base + i; if (idx < NN) s += cnt[idx]; }
    part[t] = s; __syncthreads();
    for (int st = 1; st < 1024; st <<= 1) {
        const int v = (t >= st) ? part[t - st] : 0;
        __syncthreads();
        part[t] += v;
        __syncthreads();
    }
    int run = (t == 0) ? 0 : part[t - 1];
    for (int i = 0; i < per; ++i) {
        const int idx = base + i;
        if (idx < NN) { cur[idx] = run; run += cnt[idx]; }
    }
}

__global__ void scatter_kernel(const int* __restrict__ ei, int* __restrict__ cur,
                               int* __restrict__ sidx, int* __restrict__ ssrc,
                               int* __restrict__ sdst) {
    const int e = blockIdx.x * 256 + threadIdx.x;      // NE exact
    const int d = ei[NE + e];
    const int p = atomicAdd(&cur[d], 1);
    sidx[p] = e; ssrc[p] = ei[e]; sdst[p] = d;
}

// dist in SORTED edge order
__global__ void dist_kernel(const float* __restrict__ pos, const int* __restrict__ sidx,
                            const int* __restrict__ ssrc, const int* __restrict__ sdst,
                            const float* __restrict__ cell, const float* __restrict__ U,
                            float* __restrict__ dist) {
    const int p = blockIdx.x * 256 + threadIdx.x;      // NE exact
    const int e = sidx[p];
    const int s = ssrc[p], d = sdst[p];
    const float c0 = cell[e*3], c1 = cell[e*3+1], c2 = cell[e*3+2];
    const float ox = c0*U[0] + c1*U[3] + c2*U[6];
    const float oy = c0*U[1] + c1*U[4] + c2*U[7];
    const float oz = c0*U[2] + c1*U[5] + c2*U[8];
    const float dx = pos[d*3]   - ox - pos[s*3];
    const float dy = pos[d*3+1] - oy - pos[s*3+1];
    const float dz = pos[d*3+2] - oz - pos[s*3+2];
    dist[p] = sqrtf(dx*dx + dy*dy + dz*dz);
}

// ---------------------------------------------------------------------------
// Edge MLP, dst-sorted, 64 edges/block, NO LDS A-tile: MFMA A-fragments are
// 16B contiguous slices of hb[node] loaded straight from global. LDS holds
// only the wave-private t1/msg buffer (64 rows x 256B, XOR-swizzled).
// ---------------------------------------------------------------------------
__global__ __launch_bounds__(256, 5) void edge_kernel(
    const unsigned short* __restrict__ hb, const float* __restrict__ dist,
    const int* __restrict__ ssrc, const int* __restrict__ sdst,
    const unsigned short* __restrict__ pw,
    const float* __restrict__ w1last, const float* __restrict__ b1,
    const float* __restrict__ g1, const float* __restrict__ be1,
    const float* __restrict__ b2, const float* __restrict__ g2,
    const float* __restrict__ be2, float* __restrict__ aggr)
{
    __shared__ unsigned short lds[64 * 128];           // 64 rows x 256B
    char* ldsb = (char*)lds;
    const int tid = threadIdx.x, blk = blockIdx.x;
    const int l = tid & 63, wv = tid >> 6;
    const int mbase = wv * 16;
    const int li = l & 15, gq = l >> 4;
    const int arow = mbase + li;
    const int asw = (arow & 7) << 4;

    const int erow = blk*64 + arow;
    const int dn = sdst[erow], sn = ssrc[erow];
    const unsigned short* pD = hb + dn*HD + gq*8;
    const unsigned short* pS = hb + sn*HD + gq*8;

    f4 acc[8];
    #pragma unroll
    for (int f = 0; f < 8; ++f) { f4 z = {0.f,0.f,0.f,0.f}; acc[f] = z; }
    #pragma unroll
    for (int s = 0; s < 8; ++s) {
        const bf8 a = (s < 4) ? *(const bf8*)(pD + s*32) : *(const bf8*)(pS + (s-4)*32);
        #pragma unroll
        for (int f = 0; f < 8; ++f) {
            bf8 b = *(const bf8*)(pw + s*4096 + f*512 + l*8);
            acc[f] = __builtin_amdgcn_mfma_f32_16x16x32_bf16(a, b, acc[f], 0, 0, 0);
        }
    }

    // epilogue 1: +b1 +dist*w1last -> LN -> relu -> bf16 t1 into LDS
    float dsv[4];
    #pragma unroll
    for (int r = 0; r < 4; ++r) dsv[r] = dist[blk*64 + mbase + gq*4 + r];
    float bb[8], wl[8];
    float ps[4] = {0,0,0,0}, pq[4] = {0,0,0,0};
    #pragma unroll
    for (int f = 0; f < 8; ++f) {
        const int n = f*16 + li;
        bb[f] = b1[n]; wl[f] = w1last[n];
        #pragma unroll
        for (int r = 0; r < 4; ++r) {
            const float v = acc[f][r] + bb[f] + dsv[r]*wl[f];
            ps[r] += v; pq[r] += v*v;
        }
    }
    #pragma unroll
    for (int m = 1; m < 16; m <<= 1) {
        #pragma unroll
        for (int r = 0; r < 4; ++r) {
            ps[r] += __shfl_xor(ps[r], m);
            pq[r] += __shfl_xor(pq[r], m);
        }
    }
    #pragma unroll
    for (int r = 0; r < 4; ++r) {
        const float mean = ps[r] * (1.f/HD);
        const float rstd = rsqrtf(pq[r]*(1.f/HD) - mean*mean + LNEPS);
        const int row = mbase + gq*4 + r;
        const int rsw = (row & 7) << 4;
        #pragma unroll
        for (int f = 0; f < 8; ++f) {
            const int n = f*16 + li;
            float v = (acc[f][r] + bb[f] + dsv[r]*wl[f] - mean)*rstd*g1[n] + be1[n];
            v = fmaxf(v, 0.f);
            *(unsigned short*)(ldsb + ((row*256 + n*2) ^ rsw)) = f2bf(v);
        }
    }
    // rows are wave-private: no barrier before GEMM2

    const unsigned short* pw2 = pw + 32768;
    f4 acc2[8];
    #pragma unroll
    for (int f = 0; f < 8; ++f) { f4 z = {0.f,0.f,0.f,0.f}; acc2[f] = z; }
    #pragma unroll
    for (int s = 0; s < 4; ++s) {
        bf8 a = *(const bf8*)(ldsb + ((arow*256 + s*64 + gq*16) ^ asw));
        #pragma unroll
        for (int f = 0; f < 8; ++f) {
            bf8 b = *(const bf8*)(pw2 + s*4096 + f*512 + l*8);
            acc2[f] = __builtin_amdgcn_mfma_f32_16x16x32_bf16(a, b, acc2[f], 0, 0, 0);
        }
    }

    // epilogue 2: +b2 -> LN -> relu -> bf16 msg overwrites t1 rows (wave-private)
    float bb2[8];
    float ps2[4] = {0,0,0,0}, pq2[4] = {0,0,0,0};
    #pragma unroll
    for (int f = 0; f < 8; ++f) {
        bb2[f] = b2[f*16 + li];
        #pragma unroll
        for (int r = 0; r < 4; ++r) {
            const float v = acc2[f][r] + bb2[f];
            ps2[r] += v; pq2[r] += v*v;
        }
    }
    #pragma unroll
    for (int m = 1; m < 16; m <<= 1) {
        #pragma unroll
        for (int r = 0; r < 4; ++r) {
            ps2[r] += __shfl_xor(ps2[r], m);
            pq2[r] += __shfl_xor(pq2[r], m);
        }
    }
    #pragma unroll
    for (int r = 0; r < 4; ++r) {
        const float mean = ps2[r] * (1.f/HD);
        const float rstd = rsqrtf(pq2[r]*(1.f/HD) - mean*mean + LNEPS);
        const int row = mbase + gq*4 + r;
        const int rsw = (row & 7) << 4;
        #pragma unroll
        for (int f = 0; f < 8; ++f) {
            const int n = f*16 + li;
            float v = (acc2[f][r] + bb2[f] - mean)*rstd*g2[n] + be2[n];
            *(unsigned short*)(ldsb + ((row*256 + n*2) ^ rsw)) = f2bf(fmaxf(v, 0.f));
        }
    }
    __syncthreads();

    // segmented reduce: thread = (col-pair j2, row-quarter q)
    {
        const int j2 = tid & 63, q = tid >> 6;
        int curd = sdst[blk*64 + q*16];
        float a0 = 0.f, a1 = 0.f;
        #pragma unroll 4
        for (int i = 0; i < 16; ++i) {
            const int row = q*16 + i;
            const int d = sdst[blk*64 + row];
            const unsigned int u = *(const unsigned int*)(ldsb + ((row*256 + j2*4) ^ ((row & 7) << 4)));
            if (d != curd) {
                unsafeAtomicAdd(&aggr[curd*HD + 2*j2],     a0);
                unsafeAtomicAdd(&aggr[curd*HD + 2*j2 + 1], a1);
                a0 = a1 = 0.f; curd = d;
            }
            a0 += __uint_as_float(u << 16);
            a1 += __uint_as_float(u & 0xffff0000u);
        }
        unsafeAtomicAdd(&aggr[curd*HD + 2*j2],     a0);
        unsafeAtomicAdd(&aggr[curd*HD + 2*j2 + 1], a1);
    }
}

// ---------------------------------------------------------------------------
// Node update, no LDS A-tile: h-half from hb (bf16 direct), aggr-half loaded
// f32 and packed to bf16 in-register. Residual h += u, refresh hb.
// ---------------------------------------------------------------------------
__global__ __launch_bounds__(256, 5) void node_kernel(
    unsigned short* __restrict__ hb, const float* __restrict__ aggr,
    const unsigned short* __restrict__ pw,
    const float* __restrict__ b1, const float* __restrict__ g1, const float* __restrict__ be1,
    const float* __restrict__ b2, const float* __restrict__ g2, const float* __restrict__ be2,
    float* __restrict__ h)
{
    __shared__ unsigned short lds[64 * 128];
    char* ldsb = (char*)lds;
    const int tid = threadIdx.x, blk = blockIdx.x;
    const int l = tid & 63, wv = tid >> 6;
    const int mbase = wv * 16;
    const int li = l & 15, gq = l >> 4;
    const int arow = mbase + li;
    const int asw = (arow & 7) << 4;

    const int nodeA = blk*64 + arow;
    const int nc = (nodeA < NN) ? nodeA : NN - 1;
    const unsigned short* pH = hb + nc*HD + gq*8;
    const float* pA = aggr + nc*HD + gq*8;

    f4 acc[8];
    #pragma unroll
    for (int f = 0; f < 8; ++f) { f4 z = {0.f,0.f,0.f,0.f}; acc[f] = z; }
    #pragma unroll
    for (int s = 0; s < 8; ++s) {
        bf8 a;
        if (s < 4) {
            a = *(const bf8*)(pH + s*32);
        } else {
            const float4 f0 = *(const float4*)(pA + (s-4)*32);
            const float4 f1 = *(const float4*)(pA + (s-4)*32 + 4);
            union { unsigned short u[8]; bf8 v; } pk;
            pk.u[0]=f2bf(f0.x); pk.u[1]=f2bf(f0.y); pk.u[2]=f2bf(f0.z); pk.u[3]=f2bf(f0.w);
            pk.u[4]=f2bf(f1.x); pk.u[5]=f2bf(f1.y); pk.u[6]=f2bf(f1.z); pk.u[7]=f2bf(f1.w);
            a = pk.v;
        }
        #pragma unroll
        for (int f = 0; f < 8; ++f) {
            bf8 b = *(const bf8*)(pw + s*4096 + f*512 + l*8);
            acc[f] = __builtin_amdgcn_mfma_f32_16x16x32_bf16(a, b, acc[f], 0, 0, 0);
        }
    }

    float bb[8];
    float ps[4] = {0,0,0,0}, pq[4] = {0,0,0,0};
    #pragma unroll
    for (int f = 0; f < 8; ++f) {
        bb[f] = b1[f*16 + li];
        #pragma unroll
        for (int r = 0; r < 4; ++r) {
            const float v = acc[f][r] + bb[f];
            ps[r] += v; pq[r] += v*v;
        }
    }
    #pragma unroll
    for (int m = 1; m < 16; m <<= 1) {
        #pragma unroll
        for (int r = 0; r < 4; ++r) {
            ps[r] += __shfl_xor(ps[r], m);
            pq[r] += __shfl_xor(pq[r], m);
        }
    }
    #pragma unroll
    for (int r = 0; r < 4; ++r) {
        const float mean = ps[r] * (1.f/HD);
        const float rstd = rsqrtf(pq[r]*(1.f/HD) - mean*mean + LNEPS);
        const int row = mbase + gq*4 + r;
        const int rsw = (row & 7) << 4;
        #pragma unroll
        for (int f = 0; f < 8; ++f) {
            const int n = f*16 + li;
            float v = (acc[f][r] + bb[f] - mean)*rstd*g1[n] + be1[n];
            v = fmaxf(v, 0.f);
            *(unsigned short*)(ldsb + ((row*256 + n*2) ^ rsw)) = f2bf(v);
        }
    }

    const unsigned short* pw2 = pw + 32768;
    f4 acc2[8];
    #pragma unroll
    for (int f = 0; f < 8; ++f) { f4 z = {0.f,0.f,0.f,0.f}; acc2[f] = z; }
    #pragma unroll
    for (int s = 0; s < 4; ++s) {
        bf8 a = *(const bf8*)(ldsb + ((arow*256 + s*64 + gq*16) ^ asw));
        #pragma unroll
        for (int f = 0; f < 8; ++f) {
            bf8 b = *(const bf8*)(pw2 + s*4096 + f*512 + l*8);
            acc2[f] = __builtin_amdgcn_mfma_f32_16x16x32_bf16(a, b, acc2[f], 0, 0, 0);
        }
    }

    float bb2[8];
    float ps2[4] = {0,0,0,0}, pq2[4] = {0,0,0,0};
    #pragma unroll
    for (int f = 0; f < 8; ++f) {
        bb2[f] = b2[f*16 + li];
        #pragma unroll
        for (int r = 0; r < 4; ++r) {
            const float v = acc2[f][r] + bb2[f];
            ps2[r] += v; pq2[r] += v*v;
        }
    }
    #pragma unroll
    for (int m = 1; m < 16; m <<= 1) {
        #pragma unroll
        for (int r = 0; r < 4; ++r) {
            ps2[r] += __shfl_xor(ps2[r], m);
            pq2[r] += __shfl_xor(pq2[r], m);
        }
    }
    #pragma unroll
    for (int r = 0; r < 4; ++r) {
        const int node = blk*64 + mbase + gq*4 + r;
        if (node < NN) {
            const float mean = ps2[r] * (1.f/HD);
            const float rstd = rsqrtf(pq2[r]*(1.f/HD) - mean*mean + LNEPS);
            #pragma unroll
            for (int f = 0; f < 8; ++f) {
                const int n = f*16 + li;
                float v = (acc2[f][r] + bb2[f] - mean)*rstd*g2[n] + be2[n];
                v = fmaxf(v, 0.f);
                const int idx = node*HD + n;
                const float nh = h[idx] + v;
                h[idx] = nh;
                hb[idx] = f2bf(nh);
            }
        }
    }
}

// global_add_pool over sorted batch_ids
__global__ void pool_kernel(const float* __restrict__ h, const int* __restrict__ bids,
                            float* __restrict__ pooled) {
    const int j = threadIdx.x;                  // 128 features
    const int n0 = blockIdx.x * 256;
    if (n0 >= NN) return;
    int cur = bids[n0];
    float acc = 0.f;
    for (int i = 0; i < 256; ++i) {
        const int n = n0 + i;
        if (n >= NN) break;
        const int b = bids[n];
        if (b != cur) { unsafeAtomicAdd(&pooled[cur*HD + j], acc); acc = 0.f; cur = b; }
        acc += h[n*HD + j];
    }
    unsafeAtomicAdd(&pooled[cur*HD + j], acc);
}

__global__ void pred_kernel(const float* __restrict__ pooled, const float* __restrict__ w1,
                            const float* __restrict__ pb1, const float* __restrict__ w2,
                            const float* __restrict__ pb2, float* __restrict__ out) {
    const int g = blockIdx.x, j = threadIdx.x;  // 128 threads
    __shared__ float pg[128];
    __shared__ float red[128];
    pg[j] = pooled[g*HD + j];
    __syncthreads();
    float z = pb1[j];
    for (int k = 0; k < 128; ++k) z += pg[k] * w1[k*HD + j];
    red[j] = fmaxf(z, 0.f) * w2[j];
    __syncthreads();
    for (int st = 64; st > 0; st >>= 1) {
        if (j < st) red[j] += red[j + st];
        __syncthreads();
    }
    if (j == 0) out[g] = red[0] + pb2[0];
}

extern "C" void kernel_launch(void* const* d_in, const int* in_sizes, int n_in,
                              void* d_out, int out_size, void* d_ws, size_t ws_size,
                              hipStream_t stream) {
    const float* x       = (const float*)d_in[0];
    const float* pos     = (const float*)d_in[1];
    const int*   ei      = (const int*)  d_in[2];
    const float* cell    = (const float*)d_in[3];
    const float* U       = (const float*)d_in[4];
    const int*   bids    = (const int*)  d_in[5];
    const float* emb_w   = (const float*)d_in[6];
    const float* emb_b   = (const float*)d_in[7];
    const float* msg_w1  = (const float*)d_in[8];
    const float* msg_b1  = (const float*)d_in[9];
    const float* msg_g1  = (const float*)d_in[10];
    const float* msg_be1 = (const float*)d_in[11];
    const float* msg_w2  = (const float*)d_in[12];
    const float* msg_b2  = (const float*)d_in[13];
    const float* msg_g2  = (const float*)d_in[14];
    const float* msg_be2 = (const float*)d_in[15];
    const float* upd_w1  = (const float*)d_in[16];
    const float* upd_b1  = (const float*)d_in[17];
    const float* upd_g1  = (const float*)d_in[18];
    const float* upd_be1 = (const float*)d_in[19];
    const float* upd_w2  = (const float*)d_in[20];
    const float* upd_b2  = (const float*)d_in[21];
    const float* upd_g2  = (const float*)d_in[22];
    const float* upd_be2 = (const float*)d_in[23];
    const float* pred_w1 = (const float*)d_in[24];
    const float* pred_b1 = (const float*)d_in[25];
    const float* pred_w2 = (const float*)d_in[26];
    const float* pred_b2 = (const float*)d_in[27];

    char* ws = (char*)d_ws;
    float*          h      = (float*)          ws;                 // 25,600,000
    unsigned short* hb     = (unsigned short*)(ws + 25600000);     // 12,800,000
    float*          aggr   = (float*)         (ws + 38400000);     // 25,600,000
    float*          dist   = (float*)         (ws + 64000000);     //  3,200,000
    float*          pooled = (float*)         (ws + 67200000);     //     32,768
    unsigned short* packed = (unsigned short*)(ws + 67232768);     //    983,040
    int*            cnt    = (int*)           (ws + 68215808);     //    200,704
    int*            cur    = (int*)           (ws + 68416512);     //    200,704
    int*            sidx   = (int*)           (ws + 68617216);     //  3,200,000
    int*            ssrc   = (int*)           (ws + 71817216);     //  3,200,000
    int*            sdst   = (int*)           (ws + 75017216);     //  3,200,000

    hipMemsetAsync(aggr, 0, (size_t)NN * HD * sizeof(float), stream);
    hipMemsetAsync(pooled, 0, (size_t)NG * HD * sizeof(float), stream);
    hipMemsetAsync(cnt, 0, (size_t)NN * sizeof(int), stream);

    dim3 pgrid(128, DEPTH * 4);
    pack_weights<<<pgrid, 256, 0, stream>>>(msg_w1, msg_w2, upd_w1, upd_w2, packed);
    embed_kernel<<<(NN * HD) / 256, 256, 0, stream>>>(x, emb_w, emb_b, h, hb);

    hist_kernel<<<NE / 256, 256, 0, stream>>>(ei, cnt);
    scan_kernel<<<1, 1024, 0, stream>>>(cnt, cur);
    scatter_kernel<<<NE / 256, 256, 0, stream>>>(ei, cur, sidx, ssrc, sdst);
    dist_kernel<<<NE / 256, 256, 0, stream>>>(pos, sidx, ssrc, sdst, cell, U, dist);

    for (int layer = 0; layer < DEPTH; ++layer) {
        const unsigned short* pl = packed + layer * 98304;
        edge_kernel<<<NE / 64, 256, 0, stream>>>(
            hb, dist, ssrc, sdst, pl,
            msg_w1 + layer*257*HD + 256*HD,
            msg_b1 + layer*HD, msg_g1 + layer*HD, msg_be1 + layer*HD,
            msg_b2 + layer*HD, msg_g2 + layer*HD, msg_be2 + layer*HD,
            aggr);
        node_kernel<<<(NN + 63) / 64, 256, 0, stream>>>(
            hb, aggr, pl + 49152,
            upd_b1 + layer*HD, upd_g1 + layer*HD, upd_be1 + layer*HD,
            upd_b2 + layer*HD, upd_g2 + layer*HD, upd_be2 + layer*HD,
            h);
        hipMemsetAsync(aggr, 0, (size_t)NN * HD * sizeof(float), stream);
    }

    pool_kernel<<<(NN + 255) / 256, 128, 0, stream>>>(h, bids, pooled);
    pred_kernel<<<NG, 128, 0, stream>>>(pooled, pred_w1, pred_b1, pred_w2, pred_b2, (float*)d_out);
}

// Round 4
// 1506.750 us; speedup vs baseline: 1.5308x; 1.3867x over previous
//
#include <hip/hip_runtime.h>

#define NN 50000
#define NE 800000
#define HD 128
#define DEPTH 5
#define NG 64
#define LNEPS 1e-5f

typedef __attribute__((ext_vector_type(8))) short bf8;   // 8 x bf16
typedef __attribute__((ext_vector_type(4))) float f4;

static __device__ __forceinline__ unsigned short f2bf(float x) {
    unsigned int u = __float_as_uint(x);
    unsigned int r = (u + 0x7fffu + ((u >> 16) & 1u)) >> 16;   // RNE
    return (unsigned short)r;
}

// ---------------------------------------------------------------------------
// Pack weight matrices (K x 128 f32, row-major) into bf16 MFMA B-fragment
// layout: packed[s*4096 + f*512 + lane*8 + e] = W[s*32 + (lane>>4)*8 + e][f*16 + (lane&15)]
// ---------------------------------------------------------------------------
__global__ void pack_weights(const float* __restrict__ msg_w1, const float* __restrict__ msg_w2,
                             const float* __restrict__ upd_w1, const float* __restrict__ upd_w2,
                             unsigned short* __restrict__ packed) {
    const int which = blockIdx.y & 3, layer = blockIdx.y >> 2;
    const int t = blockIdx.x * 256 + threadIdx.x;
    const float* src; int K; unsigned short* dst;
    unsigned short* lbase = packed + layer * 98304;
    if (which == 0)      { src = msg_w1 + layer*257*HD; K = 256; dst = lbase; }
    else if (which == 1) { src = msg_w2 + layer*HD*HD;  K = 128; dst = lbase + 32768; }
    else if (which == 2) { src = upd_w1 + layer*256*HD; K = 256; dst = lbase + 49152; }
    else                 { src = upd_w2 + layer*HD*HD;  K = 128; dst = lbase + 81920; }
    if (t >= K * HD) return;
    const int e = t & 7, l = (t >> 3) & 63, f = (t >> 9) & 7, s = t >> 12;
    const int k = s*32 + ((l >> 4) << 3) + e;
    const int n = f*16 + (l & 15);
    dst[t] = f2bf(src[k*HD + n]);
}

__global__ void embed_kernel(const float* __restrict__ x, const float* __restrict__ emb_w,
                             const float* __restrict__ emb_b,
                             float* __restrict__ h, unsigned short* __restrict__ hb) {
    const int i = blockIdx.x * 256 + threadIdx.x;      // N*H exact
    const int n = i >> 7, j = i & 127;
    const float v = x[n] * emb_w[j] + emb_b[j];
    h[i] = v; hb[i] = f2bf(v);
}

// --------------------- counting sort of edges by dst -----------------------
__global__ void hist_kernel(const int* __restrict__ ei, int* __restrict__ cnt) {
    const int e = blockIdx.x * 256 + threadIdx.x;      // NE exact
    atomicAdd(&cnt[ei[NE + e]], 1);
}

__global__ __launch_bounds__(1024) void scan_kernel(const int* __restrict__ cnt,
                                                    int* __restrict__ cur) {
    __shared__ int part[1024];
    const int t = threadIdx.x;
    const int per = 49;                                 // 1024*49 >= NN
    const int base = t * per;
    int s = 0;
    for (int i = 0; i < per; ++i) { const int idx = base + i; if (idx < NN) s += cnt[idx]; }
    part[t] = s; __syncthreads();
    for (int st = 1; st < 1024; st <<= 1) {
        const int v = (t >= st) ? part[t - st] : 0;
        __syncthreads();
        part[t] += v;
        __syncthreads();
    }
    int run = (t == 0) ? 0 : part[t - 1];
    for (int i = 0; i < per; ++i) {
        const int idx = base + i;
        if (idx < NN) { cur[idx] = run; run += cnt[idx]; }
    }
}

__global__ void scatter_kernel(const int* __restrict__ ei, int* __restrict__ cur,
                               int* __restrict__ sidx, int* __restrict__ ssrc,
                               int* __restrict__ sdst) {
    const int e = blockIdx.x * 256 + threadIdx.x;      // NE exact
    const int d = ei[NE + e];
    const int p = atomicAdd(&cur[d], 1);
    sidx[p] = e; ssrc[p] = ei[e]; sdst[p] = d;
}

// dist in SORTED edge order
__global__ void dist_kernel(const float* __restrict__ pos, const int* __restrict__ sidx,
                            const int* __restrict__ ssrc, const int* __restrict__ sdst,
                            const float* __restrict__ cell, const float* __restrict__ U,
                            float* __restrict__ dist) {
    const int p = blockIdx.x * 256 + threadIdx.x;      // NE exact
    const int e = sidx[p];
    const int s = ssrc[p], d = sdst[p];
    const float c0 = cell[e*3], c1 = cell[e*3+1], c2 = cell[e*3+2];
    const float ox = c0*U[0] + c1*U[3] + c2*U[6];
    const float oy = c0*U[1] + c1*U[4] + c2*U[7];
    const float oz = c0*U[2] + c1*U[5] + c2*U[8];
    const float dx = pos[d*3]   - ox - pos[s*3];
    const float dy = pos[d*3+1] - oy - pos[s*3+1];
    const float dz = pos[d*3+2] - oz - pos[s*3+2];
    dist[p] = sqrtf(dx*dx + dy*dy + dz*dz);
}

// ---------------------------------------------------------------------------
// Edge MLP, dst-sorted, 128 edges/block, 4 waves x 32 rows (2 row-groups of 16).
// B-fragments batched (breg[8]) and reused across both row-groups -> 2 MFMA per
// B-load. A-fragments straight from global (L2/L3-hot). LDS: 32KB t1/msg buffer.
// ---------------------------------------------------------------------------
__global__ __launch_bounds__(256, 2) void edge_kernel(
    const unsigned short* __restrict__ hb, const float* __restrict__ dist,
    const int* __restrict__ ssrc, const int* __restrict__ sdst,
    const unsigned short* __restrict__ pw,
    const float* __restrict__ w1last, const float* __restrict__ b1,
    const float* __restrict__ g1, const float* __restrict__ be1,
    const float* __restrict__ b2, const float* __restrict__ g2,
    const float* __restrict__ be2, float* __restrict__ aggr)
{
    __shared__ unsigned short lds[128 * 128];          // 128 rows x 256B
    __shared__ int dstl[128];
    char* ldsb = (char*)lds;
    const int tid = threadIdx.x, blk = blockIdx.x;
    const int l = tid & 63, wv = tid >> 6;
    const int li = l & 15, gq = l >> 4;

    if (tid < 128) dstl[tid] = sdst[blk*128 + tid];

    const int rowA = wv*32 + li, rowB = rowA + 16;
    const int eA = blk*128 + rowA, eB = blk*128 + rowB;
    const unsigned short* pDA = hb + sdst[eA]*HD + gq*8;
    const unsigned short* pSA = hb + ssrc[eA]*HD + gq*8;
    const unsigned short* pDB = hb + sdst[eB]*HD + gq*8;
    const unsigned short* pSB = hb + ssrc[eB]*HD + gq*8;

    f4 acc[2][8];
    #pragma unroll
    for (int m = 0; m < 2; ++m)
        #pragma unroll
        for (int f = 0; f < 8; ++f) { f4 z = {0.f,0.f,0.f,0.f}; acc[m][f] = z; }

    #pragma unroll
    for (int s = 0; s < 8; ++s) {
        bf8 breg[8];
        #pragma unroll
        for (int f = 0; f < 8; ++f) breg[f] = *(const bf8*)(pw + s*4096 + f*512 + l*8);
        const bf8 aA = (s < 4) ? *(const bf8*)(pDA + s*32) : *(const bf8*)(pSA + (s-4)*32);
        const bf8 aB = (s < 4) ? *(const bf8*)(pDB + s*32) : *(const bf8*)(pSB + (s-4)*32);
        #pragma unroll
        for (int f = 0; f < 8; ++f) {
            acc[0][f] = __builtin_amdgcn_mfma_f32_16x16x32_bf16(aA, breg[f], acc[0][f], 0, 0, 0);
            acc[1][f] = __builtin_amdgcn_mfma_f32_16x16x32_bf16(aB, breg[f], acc[1][f], 0, 0, 0);
        }
    }

    // epilogue 1: +b1 +dist*w1last -> LN -> relu -> bf16 t1 into LDS
    float bb[8], wl[8];
    #pragma unroll
    for (int f = 0; f < 8; ++f) { const int n = f*16 + li; bb[f] = b1[n]; wl[f] = w1last[n]; }
    #pragma unroll
    for (int m = 0; m < 2; ++m) {
        float dsv[4];
        #pragma unroll
        for (int r = 0; r < 4; ++r) dsv[r] = dist[blk*128 + wv*32 + m*16 + gq*4 + r];
        float ps[4] = {0,0,0,0}, pq[4] = {0,0,0,0};
        #pragma unroll
        for (int f = 0; f < 8; ++f)
            #pragma unroll
            for (int r = 0; r < 4; ++r) {
                const float v = acc[m][f][r] + bb[f] + dsv[r]*wl[f];
                ps[r] += v; pq[r] += v*v;
            }
        #pragma unroll
        for (int mm = 1; mm < 16; mm <<= 1)
            #pragma unroll
            for (int r = 0; r < 4; ++r) {
                ps[r] += __shfl_xor(ps[r], mm);
                pq[r] += __shfl_xor(pq[r], mm);
            }
        #pragma unroll
        for (int r = 0; r < 4; ++r) {
            const float mean = ps[r] * (1.f/HD);
            const float rstd = rsqrtf(pq[r]*(1.f/HD) - mean*mean + LNEPS);
            const int row = wv*32 + m*16 + gq*4 + r;
            const int rsw = (row & 7) << 4;
            #pragma unroll
            for (int f = 0; f < 8; ++f) {
                const int n = f*16 + li;
                float v = (acc[m][f][r] + bb[f] + dsv[r]*wl[f] - mean)*rstd*g1[n] + be1[n];
                *(unsigned short*)(ldsb + ((row*256 + n*2) ^ rsw)) = f2bf(fmaxf(v, 0.f));
            }
        }
    }
    // rows are wave-private: no barrier before GEMM2

    const unsigned short* pw2 = pw + 32768;
    f4 acc2[2][8];
    #pragma unroll
    for (int m = 0; m < 2; ++m)
        #pragma unroll
        for (int f = 0; f < 8; ++f) { f4 z = {0.f,0.f,0.f,0.f}; acc2[m][f] = z; }
    #pragma unroll
    for (int s = 0; s < 4; ++s) {
        bf8 breg[8];
        #pragma unroll
        for (int f = 0; f < 8; ++f) breg[f] = *(const bf8*)(pw2 + s*4096 + f*512 + l*8);
        #pragma unroll
        for (int m = 0; m < 2; ++m) {
            const int ar = wv*32 + m*16 + li;
            const bf8 a = *(const bf8*)(ldsb + ((ar*256 + s*64 + gq*16) ^ ((ar & 7) << 4)));
            #pragma unroll
            for (int f = 0; f < 8; ++f)
                acc2[m][f] = __builtin_amdgcn_mfma_f32_16x16x32_bf16(a, breg[f], acc2[m][f], 0, 0, 0);
        }
    }

    // epilogue 2: +b2 -> LN -> relu -> bf16 msg overwrites t1 rows
    float bb2[8], gg2[8], bee2[8];
    #pragma unroll
    for (int f = 0; f < 8; ++f) {
        const int n = f*16 + li;
        bb2[f] = b2[n]; gg2[f] = g2[n]; bee2[f] = be2[n];
    }
    #pragma unroll
    for (int m = 0; m < 2; ++m) {
        float ps[4] = {0,0,0,0}, pq[4] = {0,0,0,0};
        #pragma unroll
        for (int f = 0; f < 8; ++f)
            #pragma unroll
            for (int r = 0; r < 4; ++r) {
                const float v = acc2[m][f][r] + bb2[f];
                ps[r] += v; pq[r] += v*v;
            }
        #pragma unroll
        for (int mm = 1; mm < 16; mm <<= 1)
            #pragma unroll
            for (int r = 0; r < 4; ++r) {
                ps[r] += __shfl_xor(ps[r], mm);
                pq[r] += __shfl_xor(pq[r], mm);
            }
        #pragma unroll
        for (int r = 0; r < 4; ++r) {
            const float mean = ps[r] * (1.f/HD);
            const float rstd = rsqrtf(pq[r]*(1.f/HD) - mean*mean + LNEPS);
            const int row = wv*32 + m*16 + gq*4 + r;
            const int rsw = (row & 7) << 4;
            #pragma unroll
            for (int f = 0; f < 8; ++f) {
                const int n = f*16 + li;
                float v = (acc2[m][f][r] + bb2[f] - mean)*rstd*gg2[f] + bee2[f];
                *(unsigned short*)(ldsb + ((row*256 + n*2) ^ rsw)) = f2bf(fmaxf(v, 0.f));
            }
        }
    }
    __syncthreads();

    // segmented reduce: thread = (col j, half hh of 64 rows); contiguous atomics
    {
        const int j = tid & 127, hh = tid >> 7;
        const int r0 = hh * 64;
        int curd = dstl[r0];
        float a0 = 0.f;
        #pragma unroll 4
        for (int i = 0; i < 64; ++i) {
            const int row = r0 + i;
            const int d = dstl[row];
            const unsigned short u = *(const unsigned short*)(ldsb + ((row*256 + j*2) ^ ((row & 7) << 4)));
            const float v = __uint_as_float(((unsigned int)u) << 16);
            if (d != curd) { unsafeAtomicAdd(&aggr[curd*HD + j], a0); a0 = 0.f; curd = d; }
            a0 += v;
        }
        unsafeAtomicAdd(&aggr[curd*HD + j], a0);
    }
}

// ---------------------------------------------------------------------------
// Node update, 128 nodes/block, 4 waves x 32 rows. h-half from hb (bf16),
// aggr-half f32->bf16 in-register. Zeroes aggr in-place after consumption.
// Residual h += u, refresh hb.
// ---------------------------------------------------------------------------
__global__ __launch_bounds__(256, 2) void node_kernel(
    unsigned short* __restrict__ hb, float* __restrict__ aggr,
    const unsigned short* __restrict__ pw,
    const float* __restrict__ b1, const float* __restrict__ g1, const float* __restrict__ be1,
    const float* __restrict__ b2, const float* __restrict__ g2, const float* __restrict__ be2,
    float* __restrict__ h)
{
    __shared__ unsigned short lds[128 * 128];
    char* ldsb = (char*)lds;
    const int tid = threadIdx.x, blk = blockIdx.x;
    const int l = tid & 63, wv = tid >> 6;
    const int li = l & 15, gq = l >> 4;

    const int rowA = wv*32 + li, rowB = rowA + 16;
    const int nA = blk*128 + rowA, nB = blk*128 + rowB;
    const int ncA = (nA < NN) ? nA : NN - 1;
    const int ncB = (nB < NN) ? nB : NN - 1;
    const unsigned short* pHA = hb + ncA*HD + gq*8;
    const unsigned short* pHB = hb + ncB*HD + gq*8;
    float* pAA = aggr + ncA*HD + gq*8;
    float* pAB = aggr + ncB*HD + gq*8;

    f4 acc[2][8];
    #pragma unroll
    for (int m = 0; m < 2; ++m)
        #pragma unroll
        for (int f = 0; f < 8; ++f) { f4 z = {0.f,0.f,0.f,0.f}; acc[m][f] = z; }

    #pragma unroll
    for (int s = 0; s < 8; ++s) {
        bf8 breg[8];
        #pragma unroll
        for (int f = 0; f < 8; ++f) breg[f] = *(const bf8*)(pw + s*4096 + f*512 + l*8);
        bf8 aA, aB;
        if (s < 4) {
            aA = *(const bf8*)(pHA + s*32);
            aB = *(const bf8*)(pHB + s*32);
        } else {
            const float4 a0 = *(const float4*)(pAA + (s-4)*32);
            const float4 a1 = *(const float4*)(pAA + (s-4)*32 + 4);
            const float4 b0 = *(const float4*)(pAB + (s-4)*32);
            const float4 b1v = *(const float4*)(pAB + (s-4)*32 + 4);
            union { unsigned short u[8]; bf8 v; } pk;
            pk.u[0]=f2bf(a0.x); pk.u[1]=f2bf(a0.y); pk.u[2]=f2bf(a0.z); pk.u[3]=f2bf(a0.w);
            pk.u[4]=f2bf(a1.x); pk.u[5]=f2bf(a1.y); pk.u[6]=f2bf(a1.z); pk.u[7]=f2bf(a1.w);
            aA = pk.v;
            pk.u[0]=f2bf(b0.x); pk.u[1]=f2bf(b0.y); pk.u[2]=f2bf(b0.z); pk.u[3]=f2bf(b0.w);
            pk.u[4]=f2bf(b1v.x); pk.u[5]=f2bf(b1v.y); pk.u[6]=f2bf(b1v.z); pk.u[7]=f2bf(b1v.w);
            aB = pk.v;
        }
        #pragma unroll
        for (int f = 0; f < 8; ++f) {
            acc[0][f] = __builtin_amdgcn_mfma_f32_16x16x32_bf16(aA, breg[f], acc[0][f], 0, 0, 0);
            acc[1][f] = __builtin_amdgcn_mfma_f32_16x16x32_bf16(aB, breg[f], acc[1][f], 0, 0, 0);
        }
    }

    // zero aggr slices (loads above fully consumed by MFMAs)
    {
        const float4 z = {0.f,0.f,0.f,0.f};
        #pragma unroll
        for (int s = 0; s < 4; ++s) {
            if (nA < NN) { *(float4*)(pAA + s*32) = z; *(float4*)(pAA + s*32 + 4) = z; }
            if (nB < NN) { *(float4*)(pAB + s*32) = z; *(float4*)(pAB + s*32 + 4) = z; }
        }
    }

    float bb[8];
    #pragma unroll
    for (int f = 0; f < 8; ++f) bb[f] = b1[f*16 + li];
    #pragma unroll
    for (int m = 0; m < 2; ++m) {
        float ps[4] = {0,0,0,0}, pq[4] = {0,0,0,0};
        #pragma unroll
        for (int f = 0; f < 8; ++f)
            #pragma unroll
            for (int r = 0; r < 4; ++r) {
                const float v = acc[m][f][r] + bb[f];
                ps[r] += v; pq[r] += v*v;
            }
        #pragma unroll
        for (int mm = 1; mm < 16; mm <<= 1)
            #pragma unroll
            for (int r = 0; r < 4; ++r) {
                ps[r] += __shfl_xor(ps[r], mm);
                pq[r] += __shfl_xor(pq[r], mm);
            }
        #pragma unroll
        for (int r = 0; r < 4; ++r) {
            const float mean = ps[r] * (1.f/HD);
            const float rstd = rsqrtf(pq[r]*(1.f/HD) - mean*mean + LNEPS);
            const int row = wv*32 + m*16 + gq*4 + r;
            const int rsw = (row & 7) << 4;
            #pragma unroll
            for (int f = 0; f < 8; ++f) {
                const int n = f*16 + li;
                float v = (acc[m][f][r] + bb[f] - mean)*rstd*g1[n] + be1[n];
                *(unsigned short*)(ldsb + ((row*256 + n*2) ^ rsw)) = f2bf(fmaxf(v, 0.f));
            }
        }
    }

    const unsigned short* pw2 = pw + 32768;
    f4 acc2[2][8];
    #pragma unroll
    for (int m = 0; m < 2; ++m)
        #pragma unroll
        for (int f = 0; f < 8; ++f) { f4 z = {0.f,0.f,0.f,0.f}; acc2[m][f] = z; }
    #pragma unroll
    for (int s = 0; s < 4; ++s) {
        bf8 breg[8];
        #pragma unroll
        for (int f = 0; f < 8; ++f) breg[f] = *(const bf8*)(pw2 + s*4096 + f*512 + l*8);
        #pragma unroll
        for (int m = 0; m < 2; ++m) {
            const int ar = wv*32 + m*16 + li;
            const bf8 a = *(const bf8*)(ldsb + ((ar*256 + s*64 + gq*16) ^ ((ar & 7) << 4)));
            #pragma unroll
            for (int f = 0; f < 8; ++f)
                acc2[m][f] = __builtin_amdgcn_mfma_f32_16x16x32_bf16(a, breg[f], acc2[m][f], 0, 0, 0);
        }
    }

    float bb2[8];
    #pragma unroll
    for (int f = 0; f < 8; ++f) bb2[f] = b2[f*16 + li];
    #pragma unroll
    for (int m = 0; m < 2; ++m) {
        float ps[4] = {0,0,0,0}, pq[4] = {0,0,0,0};
        #pragma unroll
        for (int f = 0; f < 8; ++f)
            #pragma unroll
            for (int r = 0; r < 4; ++r) {
                const float v = acc2[m][f][r] + bb2[f];
                ps[r] += v; pq[r] += v*v;
            }
        #pragma unroll
        for (int mm = 1; mm < 16; mm <<= 1)
            #pragma unroll
            for (int r = 0; r < 4; ++r) {
                ps[r] += __shfl_xor(ps[r], mm);
                pq[r] += __shfl_xor(pq[r], mm);
            }
        #pragma unroll
        for (int r = 0; r < 4; ++r) {
            const int node = blk*128 + wv*32 + m*16 + gq*4 + r;
            if (node < NN) {
                const float mean = ps[r] * (1.f/HD);
                const float rstd = rsqrtf(pq[r]*(1.f/HD) - mean*mean + LNEPS);
                #pragma unroll
                for (int f = 0; f < 8; ++f) {
                    const int n = f*16 + li;
                    float v = (acc2[m][f][r] + bb2[f] - mean)*rstd*g2[n] + be2[n];
                    v = fmaxf(v, 0.f);
                    const int idx = node*HD + n;
                    const float nh = h[idx] + v;
                    h[idx] = nh;
                    hb[idx] = f2bf(nh);
                }
            }
        }
    }
}

// global_add_pool over sorted batch_ids
__global__ void pool_kernel(const float* __restrict__ h, const int* __restrict__ bids,
                            float* __restrict__ pooled) {
    const int j = threadIdx.x;                  // 128 features
    const int n0 = blockIdx.x * 256;
    if (n0 >= NN) return;
    int cur = bids[n0];
    float acc = 0.f;
    for (int i = 0; i < 256; ++i) {
        const int n = n0 + i;
        if (n >= NN) break;
        const int b = bids[n];
        if (b != cur) { unsafeAtomicAdd(&pooled[cur*HD + j], acc); acc = 0.f; cur = b; }
        acc += h[n*HD + j];
    }
    unsafeAtomicAdd(&pooled[cur*HD + j], acc);
}

__global__ void pred_kernel(const float* __restrict__ pooled, const float* __restrict__ w1,
                            const float* __restrict__ pb1, const float* __restrict__ w2,
                            const float* __restrict__ pb2, float* __restrict__ out) {
    const int g = blockIdx.x, j = threadIdx.x;  // 128 threads
    __shared__ float pg[128];
    __shared__ float red[128];
    pg[j] = pooled[g*HD + j];
    __syncthreads();
    float z = pb1[j];
    for (int k = 0; k < 128; ++k) z += pg[k] * w1[k*HD + j];
    red[j] = fmaxf(z, 0.f) * w2[j];
    __syncthreads();
    for (int st = 64; st > 0; st >>= 1) {
        if (j < st) red[j] += red[j + st];
        __syncthreads();
    }
    if (j == 0) out[g] = red[0] + pb2[0];
}

extern "C" void kernel_launch(void* const* d_in, const int* in_sizes, int n_in,
                              void* d_out, int out_size, void* d_ws, size_t ws_size,
                              hipStream_t stream) {
    const float* x       = (const float*)d_in[0];
    const float* pos     = (const float*)d_in[1];
    const int*   ei      = (const int*)  d_in[2];
    const float* cell    = (const float*)d_in[3];
    const float* U       = (const float*)d_in[4];
    const int*   bids    = (const int*)  d_in[5];
    const float* emb_w   = (const float*)d_in[6];
    const float* emb_b   = (const float*)d_in[7];
    const float* msg_w1  = (const float*)d_in[8];
    const float* msg_b1  = (const float*)d_in[9];
    const float* msg_g1  = (const float*)d_in[10];
    const float* msg_be1 = (const float*)d_in[11];
    const float* msg_w2  = (const float*)d_in[12];
    const float* msg_b2  = (const float*)d_in[13];
    const float* msg_g2  = (const float*)d_in[14];
    const float* msg_be2 = (const float*)d_in[15];
    const float* upd_w1  = (const float*)d_in[16];
    const float* upd_b1  = (const float*)d_in[17];
    const float* upd_g1  = (const float*)d_in[18];
    const float* upd_be1 = (const float*)d_in[19];
    const float* upd_w2  = (const float*)d_in[20];
    const float* upd_b2  = (const float*)d_in[21];
    const float* upd_g2  = (const float*)d_in[22];
    const float* upd_be2 = (const float*)d_in[23];
    const float* pred_w1 = (const float*)d_in[24];
    const float* pred_b1 = (const float*)d_in[25];
    const float* pred_w2 = (const float*)d_in[26];
    const float* pred_b2 = (const float*)d_in[27];

    char* ws = (char*)d_ws;
    float*          h      = (float*)          ws;                 // 25,600,000
    unsigned short* hb     = (unsigned short*)(ws + 25600000);     // 12,800,000
    float*          aggr   = (float*)         (ws + 38400000);     // 25,600,000
    float*          dist   = (float*)         (ws + 64000000);     //  3,200,000
    float*          pooled = (float*)         (ws + 67200000);     //     32,768
    unsigned short* packed = (unsigned short*)(ws + 67232768);     //    983,040
    int*            cnt    = (int*)           (ws + 68215808);     //    200,704
    int*            cur    = (int*)           (ws + 68416512);     //    200,704
    int*            sidx   = (int*)           (ws + 68617216);     //  3,200,000
    int*            ssrc   = (int*)           (ws + 71817216);     //  3,200,000
    int*            sdst   = (int*)           (ws + 75017216);     //  3,200,000

    hipMemsetAsync(aggr, 0, (size_t)NN * HD * sizeof(float), stream);
    hipMemsetAsync(pooled, 0, (size_t)NG * HD * sizeof(float), stream);
    hipMemsetAsync(cnt, 0, (size_t)NN * sizeof(int), stream);

    dim3 pgrid(128, DEPTH * 4);
    pack_weights<<<pgrid, 256, 0, stream>>>(msg_w1, msg_w2, upd_w1, upd_w2, packed);
    embed_kernel<<<(NN * HD) / 256, 256, 0, stream>>>(x, emb_w, emb_b, h, hb);

    hist_kernel<<<NE / 256, 256, 0, stream>>>(ei, cnt);
    scan_kernel<<<1, 1024, 0, stream>>>(cnt, cur);
    scatter_kernel<<<NE / 256, 256, 0, stream>>>(ei, cur, sidx, ssrc, sdst);
    dist_kernel<<<NE / 256, 256, 0, stream>>>(pos, sidx, ssrc, sdst, cell, U, dist);

    for (int layer = 0; layer < DEPTH; ++layer) {
        const unsigned short* pl = packed + layer * 98304;
        edge_kernel<<<NE / 128, 256, 0, stream>>>(
            hb, dist, ssrc, sdst, pl,
            msg_w1 + layer*257*HD + 256*HD,
            msg_b1 + layer*HD, msg_g1 + layer*HD, msg_be1 + layer*HD,
            msg_b2 + layer*HD, msg_g2 + layer*HD, msg_be2 + layer*HD,
            aggr);
        node_kernel<<<(NN + 127) / 128, 256, 0, stream>>>(
            hb, aggr, pl + 49152,
            upd_b1 + layer*HD, upd_g1 + layer*HD, upd_be1 + layer*HD,
            upd_b2 + layer*HD, upd_g2 + layer*HD, upd_be2 + layer*HD,
            h);
    }

    pool_kernel<<<(NN + 255) / 256, 128, 0, stream>>>(h, bids, pooled);
    pred_kernel<<<NG, 128, 0, stream>>>(pooled, pred_w1, pred_b1, pred_w2, pred_b2, (float*)d_out);
}